// Round 9
// baseline (187.720 us; speedup 1.0000x reference)
//
#include <hip/hip_runtime.h>
#include <stdint.h>

// SimCLR loss, B=4096, D=512, TAU=0.1.  out[0]=loss, out[1]=acc(%).
//
// Round 9: barrier-free K-loop. Rounds 5-8 all plateaued at 80-107us /
// MfmaUtil<=37% on the LDS+__syncthreads structure (the documented m97
// 2-barrier plateau: every barrier drains vmcnt(0) for all waves at once).
// Fix: prep writes a SECOND copy of the fp8 operands in B-fragment-coalesced
// "column tile" layout (tile ct: chunk kc2 -> 1KB block, lane*16B), so the
// tiles kernel loads B-fragments straight global->VGPR with coalesced
// dwordx4. No LDS staging, no ds_read, no __syncthreads in the loop ->
// compiler emits progressive s_waitcnt vmcnt(N) (AITER-style), waves free-
// run. A raw s_barrier (no drain) per tile keeps the block's 4 waves
// co-paced so L1 serves the 16KB tile to all 4 (L2 ~270MB total).
// Fixed-max softmax (logits bounded by 10) -> additive partials, atomicAdd;
// row-max for accuracy via atomicMax (pass A only). Label exact fp32.

#define BN 4096
#define DK 512            // K elements = bytes per row in fp8
#define NEG_BIG -1e30f
#define SCL 0.15625f      // 1/(8*8*TAU): undo fp8 pre-scale 8 (both sides), /tau
#define CT_BYTES 16384    // one 32-col fragment-layout tile (32 cols x 512B)

typedef __attribute__((ext_vector_type(16))) float floatx16;

// ---------------- prep: normalize, fp8-pack, row+col layouts, label -------
// Row (permuted) layout, per row: byte kc2*32 + h*16 + t*8 + j holds original
// k = kc2*32 + t*16 + h*8 + j; 16B chunk (kc2,h) = A-frags for kc=2kc2,2kc2+1.
// Col layout, per 32-row tile ct: chunk kc2 is a 1KB block; lane (h*32+n5)
// holds row (ct*32+n5)'s chunk (kc2,h) at offset lane*16 -> one coalesced
// dwordx4 per (tile, kc2) in the consumer.
__global__ void __launch_bounds__(256) prep_kernel(
    const float* __restrict__ A, const float* __restrict__ Bv,
    unsigned char* __restrict__ An, unsigned char* __restrict__ Bn,
    unsigned char* __restrict__ Acol, unsigned char* __restrict__ Bcol,
    float* __restrict__ diag, float* __restrict__ zero_region) {
  {  // zero accLA/accLB/accMA/cnt (harness poisons ws with 0xAA)
    const int idx = blockIdx.x * 256 + threadIdx.x;
    if (idx < 3 * BN + 1) zero_region[idx] = 0.0f;
  }
  const int w = threadIdx.x >> 6, lane = threadIdx.x & 63;
  const int row = blockIdx.x * 4 + w;
  const float4* pa4 = (const float4*)(A + (size_t)row * DK);
  const float4* pb4 = (const float4*)(Bv + (size_t)row * DK);
  float4 a0 = pa4[lane * 2], a1 = pa4[lane * 2 + 1];  // k = lane*8 .. +7
  float4 b0 = pb4[lane * 2], b1 = pb4[lane * 2 + 1];
  float ssa = a0.x * a0.x + a0.y * a0.y + a0.z * a0.z + a0.w * a0.w +
              a1.x * a1.x + a1.y * a1.y + a1.z * a1.z + a1.w * a1.w;
  float ssb = b0.x * b0.x + b0.y * b0.y + b0.z * b0.z + b0.w * b0.w +
              b1.x * b1.x + b1.y * b1.y + b1.z * b1.z + b1.w * b1.w;
  float sab = a0.x * b0.x + a0.y * b0.y + a0.z * b0.z + a0.w * b0.w +
              a1.x * b1.x + a1.y * b1.y + a1.z * b1.z + a1.w * b1.w;
#pragma unroll
  for (int off = 32; off > 0; off >>= 1) {
    ssa += __shfl_xor(ssa, off);
    ssb += __shfl_xor(ssb, off);
    sab += __shfl_xor(sab, off);
  }
  float na = fmaxf(sqrtf(ssa), 1e-12f);
  float nb = fmaxf(sqrtf(ssb), 1e-12f);
  const float s = 8.0f;  // fp8 pre-scale: keeps elems mid-range in e4m3
  float sa = s / na, sb = s / nb;
  // this lane's k-range maps to: kc2 = lane>>2, h = lane&1, t = (lane>>1)&1
  const int kc2 = lane >> 2, hh = lane & 1, tt = (lane >> 1) & 1;
  const int doff = kc2 * 32 + hh * 16 + tt * 8;  // row-layout byte pos
  const int ct = row >> 5, n5r = row & 31;       // col-layout tile coords
  const size_t coff = (size_t)ct * CT_BYTES + kc2 * 1024 + (hh * 32 + n5r) * 16 + tt * 8;
  {
    int v0 = __builtin_amdgcn_cvt_pk_fp8_f32(a0.x * sa, a0.y * sa, 0, false);
    v0 = __builtin_amdgcn_cvt_pk_fp8_f32(a0.z * sa, a0.w * sa, v0, true);
    int v1 = __builtin_amdgcn_cvt_pk_fp8_f32(a1.x * sa, a1.y * sa, 0, false);
    v1 = __builtin_amdgcn_cvt_pk_fp8_f32(a1.z * sa, a1.w * sa, v1, true);
    int2 pv; pv.x = v0; pv.y = v1;
    *(int2*)(An + (size_t)row * DK + doff) = pv;
    *(int2*)(Acol + coff) = pv;
  }
  {
    int v0 = __builtin_amdgcn_cvt_pk_fp8_f32(b0.x * sb, b0.y * sb, 0, false);
    v0 = __builtin_amdgcn_cvt_pk_fp8_f32(b0.z * sb, b0.w * sb, v0, true);
    int v1 = __builtin_amdgcn_cvt_pk_fp8_f32(b1.x * sb, b1.y * sb, 0, false);
    v1 = __builtin_amdgcn_cvt_pk_fp8_f32(b1.z * sb, b1.w * sb, v1, true);
    int2 pv; pv.x = v0; pv.y = v1;
    *(int2*)(Bn + (size_t)row * DK + doff) = pv;
    *(int2*)(Bcol + coff) = pv;
  }
  if (lane == 0) diag[row] = (sab / (na * nb)) * 10.0f;  // exact fp32 /TAU
}

// ---------------- tiles: fp8 MFMA, direct-from-global B-frags -------------
// grid = (32 row-blocks, 32 col-splits) = 1024 blocks. 4 waves/block, wave
// owns 32 rows. 256 unified 32-col tiles; split owns 8. Pass 0: a-frags ->
// full_a sums+max. Pass 1: b-frags -> full_b sums.
__global__ void __launch_bounds__(256, 2) tiles_kernel(
    const unsigned char* __restrict__ An, const unsigned char* __restrict__ Bn,
    const unsigned char* __restrict__ Acol, const unsigned char* __restrict__ Bcol,
    const float* __restrict__ diag,
    float* __restrict__ accLA, float* __restrict__ accLB,
    unsigned* __restrict__ accMA, unsigned* __restrict__ cnt,
    float* __restrict__ out) {
  const int rb = blockIdx.x;     // 0..31 (128-row panel)
  const int split = blockIdx.y;  // 0..31 (8 j-tiles of 32 cols each)
  const int tid = threadIdx.x;
  const int lane = tid & 63, w = tid >> 6;
  const int n5 = lane & 31, h = lane >> 5;
  const int r0 = rb * 128;
  const int myrow = r0 + w * 32 + n5;

  // one view's left fragments (row-permuted layout: one long2 = 2 kc frags)
  long af[32];
  auto loadfrags = [&](const unsigned char* base) {
    const unsigned char* p = base + (size_t)myrow * DK + h * 16;
#pragma unroll
    for (int kc2 = 0; kc2 < 16; ++kc2) {
      long2 v = *(const long2*)(p + kc2 * 32);
      af[2 * kc2] = v.x; af[2 * kc2 + 1] = v.y;
    }
  };

  // fixed-max state: l[r] = sum exp(logit-10); mx[r] = max acc (pass A only)
  float l[16], mx[16];
#pragma unroll
  for (int r = 0; r < 16; ++r) { l[r] = 0.f; mx[r] = NEG_BIG; }

  // sum-reduce l (and max-reduce mx) across the 32 n5-lanes, accumulate
  auto flush = [&](float* accL, bool doMax) {
#pragma unroll
    for (int off = 1; off < 32; off <<= 1)
#pragma unroll
      for (int r = 0; r < 16; ++r) {
        l[r] += __shfl_xor(l[r], off);
        if (doMax) mx[r] = fmaxf(mx[r], __shfl_xor(mx[r], off));
      }
    if (n5 == 0) {
#pragma unroll
      for (int r = 0; r < 16; ++r) {
        const int row = r0 + w * 32 + (r & 3) + 8 * (r >> 2) + 4 * h;
        atomicAdd(&accL[row], l[r]);
        if (doMax)  // encode logit+20 (>0) so uint order == float order
          atomicMax(&accMA[row], __float_as_uint(mx[r] * SCL + 20.0f));
      }
    }
#pragma unroll
    for (int r = 0; r < 16; ++r) { l[r] = 0.f; mx[r] = NEG_BIG; }
  };

#pragma unroll
  for (int pass = 0; pass < 2; ++pass) {
    loadfrags(pass == 0 ? An : Bn);
    for (int t = 0; t < 8; ++t) {
      const int jt = split * 8 + t;
      // B-frag tile in fragment-coalesced layout: chunk kc2 at kc2*1024,
      // lane*16. One dwordx4 per (kc2) per lane, fully coalesced (1KB/inst).
      const unsigned char* tb =
          ((jt < 128) ? Acol : Bcol) + (size_t)(jt & 127) * CT_BYTES + lane * 16;

      floatx16 acc;
#pragma unroll
      for (int r = 0; r < 16; ++r) acc[r] = 0.f;
#pragma unroll
      for (int kc2 = 0; kc2 < 16; ++kc2) {
        long2 bv = *(const long2*)(tb + kc2 * 1024);
        acc = __builtin_amdgcn_mfma_f32_32x32x16_fp8_fp8(af[2 * kc2], bv.x, acc, 0, 0, 0);
        acc = __builtin_amdgcn_mfma_f32_32x32x16_fp8_fp8(af[2 * kc2 + 1], bv.y, acc, 0, 0, 0);
      }

      // epilogue: mask (i,i) of this half (aa/bb masked diag AND ab label —
      // label re-added exactly in finalize), then exp-sum at fixed max 10.
      const bool dtile = (((jt & 127) >> 2) == rb);
      const int colbase = (jt & 127) * 32;
#pragma unroll
      for (int r = 0; r < 16; ++r) {
        float v0 = acc[r];
        if (dtile) {
          const int rowg = r0 + w * 32 + (r & 3) + 8 * (r >> 2) + 4 * h;
          if (rowg == colbase + n5) v0 = NEG_BIG;
        }
        if (pass == 0) mx[r] = fmaxf(mx[r], v0);
        l[r] += __expf(v0 * SCL - 10.0f);
      }
      // raw pacing barrier: keeps the block's 4 waves on the same tile so
      // L1 serves all 4 (no memory semantics -> no vmcnt drain inserted)
      __builtin_amdgcn_s_barrier();
    }
    flush(pass == 0 ? accLA : accLB, pass == 0);
  }

  // ---- last-block finalize ----
  __shared__ unsigned sflag;
  __shared__ float red[8];
  __syncthreads();  // all flush atomics of this block issued
  if (tid == 0) {
    __threadfence();  // release our atomics before the counter bump
    unsigned old = atomicAdd(cnt, 1u);
    sflag = (old == gridDim.x * gridDim.y - 1) ? 1u : 0u;
  }
  __syncthreads();
  if (sflag) {
    __threadfence();  // acquire: see all blocks' accumulates
    float lsum = 0.f, csum = 0.f;
#pragma unroll
    for (int i = 0; i < 16; ++i) {
      const int row = tid + i * 256;
      float La = accLA[row], Lb = accLB[row];
      float Mu = __uint_as_float(accMA[row]) - 20.0f;  // max non-label logit
      float d = diag[row];
      float e = __expf(d - 10.0f);                     // label term
      lsum += (20.0f + logf(La + e) + logf(Lb + e)) - 2.0f * d;
      csum += (d >= Mu) ? 1.f : 0.f;                   // argmax==label
    }
#pragma unroll
    for (int off = 32; off > 0; off >>= 1) {
      lsum += __shfl_xor(lsum, off);
      csum += __shfl_xor(csum, off);
    }
    if (lane == 0) { red[w * 2] = lsum; red[w * 2 + 1] = csum; }
    __syncthreads();
    if (tid == 0) {
      float L = red[0] + red[2] + red[4] + red[6];
      float C = red[1] + red[3] + red[5] + red[7];
      out[0] = L * (1.0f / 8192.0f);    // mean over 4096 rows, /2
      out[1] = C * (100.0f / 4096.0f);  // accuracy %
    }
  }
}

extern "C" void kernel_launch(void* const* d_in, const int* in_sizes, int n_in,
                              void* d_out, int out_size, void* d_ws, size_t ws_size,
                              hipStream_t stream) {
  const float* A = (const float*)d_in[0];
  const float* Bv = (const float*)d_in[1];
  unsigned char* An = (unsigned char*)d_ws;                   // 4096x512 fp8 (row)
  unsigned char* Bn = An + (size_t)BN * DK;                   // 4096x512 fp8 (row)
  unsigned char* Acol = Bn + (size_t)BN * DK;                 // 128 tiles x 16KB
  unsigned char* Bcol = Acol + (size_t)BN * DK;               // 128 tiles x 16KB
  float* diag = (float*)(Bcol + (size_t)BN * DK);             // 4096 f32
  float* accLA = diag + BN;                                   // 4096 f32
  float* accLB = accLA + BN;                                  // 4096 f32
  unsigned* accMA = (unsigned*)(accLB + BN);                  // 4096 u32
  unsigned* cnt = accMA + BN;                                 // 1 u32
  float* out = (float*)d_out;

  prep_kernel<<<BN / 4, 256, 0, stream>>>(A, Bv, An, Bn, Acol, Bcol, diag, accLA);
  tiles_kernel<<<dim3(32, 32), 256, 0, stream>>>(An, Bn, Acol, Bcol, diag,
                                                 accLA, accLB, accMA, cnt, out);
}

// Round 10
// 122.999 us; speedup vs baseline: 1.5262x; 1.5262x over previous
//
#include <hip/hip_runtime.h>
#include <stdint.h>

// SimCLR loss, B=4096, D=512, TAU=0.1.  out[0]=loss, out[1]=acc(%).
//
// Round 10: round-5 skeleton (best measured: 80us tiles, 2 blocks/CU, 64KB
// dbuf LDS, 64-col fp8 tiles, 2 passes a/b) with per-iteration work cut:
//  - MX-scaled mfma_scale_f32_32x32x64_f8f6f4 (scales=1.0, fmt=fp8): 2x MFMA
//    rate, 4x fewer MFMA insts, and 2 ds_read_b128 per MFMA (was 4) since the
//    K-permuted chunk layout composes K=64 operands from two K=16 chunks.
//  - Fixed-max softmax (logits bounded by 10): per-value epilogue is
//    fma+exp2+add, no online-rescale serial chains. Per-split partial
//    sums/max via PLAIN stores (no atomics; round-6's mistake avoided).
//  - Label logit exact fp32 (prep); diag masked in-kernel; separate finalize.

#define BN 4096
#define DK 512            // K elements = bytes per row in fp8
#define NSPLIT 16
#define NEG_BIG -1e30f
#define SCL 0.15625f      // 1/(8*8*TAU)
#define SCL2 0.225396744f // SCL * log2(e)
#define C2 14.4269504f    // 10 * log2(e)
#define TILE_BYTES (64 * DK)  // 32 KB per 64-col fp8 tile

typedef __attribute__((ext_vector_type(16))) float floatx16;
typedef __attribute__((ext_vector_type(8))) int intx8;

// ---------------- prep: normalize, fp8-pack (K-permuted), label, zero -----
// Permuted layout: byte position kc2*32 + h*16 + t*8 + j holds original
// k = kc2*32 + t*16 + h*8 + j.  16B chunk (kc2,h) = K=16-sub-block operand
// bytes; two consecutive chunks (2i,h),(2i+1,h) = one K=64 MX operand half.
__global__ void __launch_bounds__(256) prep_kernel(
    const float* __restrict__ A, const float* __restrict__ Bv,
    unsigned char* __restrict__ An, unsigned char* __restrict__ Bn,
    float* __restrict__ diag, float* __restrict__ out) {
  if (blockIdx.x == 0 && threadIdx.x < 2) out[threadIdx.x] = 0.0f;
  const int w = threadIdx.x >> 6, lane = threadIdx.x & 63;
  const int row = blockIdx.x * 4 + w;
  const float4* pa4 = (const float4*)(A + (size_t)row * DK);
  const float4* pb4 = (const float4*)(Bv + (size_t)row * DK);
  float4 a0 = pa4[lane * 2], a1 = pa4[lane * 2 + 1];  // k = lane*8 .. +7
  float4 b0 = pb4[lane * 2], b1 = pb4[lane * 2 + 1];
  float ssa = a0.x * a0.x + a0.y * a0.y + a0.z * a0.z + a0.w * a0.w +
              a1.x * a1.x + a1.y * a1.y + a1.z * a1.z + a1.w * a1.w;
  float ssb = b0.x * b0.x + b0.y * b0.y + b0.z * b0.z + b0.w * b0.w +
              b1.x * b1.x + b1.y * b1.y + b1.z * b1.z + b1.w * b1.w;
  float sab = a0.x * b0.x + a0.y * b0.y + a0.z * b0.z + a0.w * b0.w +
              a1.x * b1.x + a1.y * b1.y + a1.z * b1.z + a1.w * b1.w;
#pragma unroll
  for (int off = 32; off > 0; off >>= 1) {
    ssa += __shfl_xor(ssa, off);
    ssb += __shfl_xor(ssb, off);
    sab += __shfl_xor(sab, off);
  }
  float na = fmaxf(sqrtf(ssa), 1e-12f);
  float nb = fmaxf(sqrtf(ssb), 1e-12f);
  const float s = 8.0f;  // fp8 pre-scale: keeps elems mid-range in e4m3
  float sa = s / na, sb = s / nb;
  const int doff = (lane >> 2) * 32 + (lane & 1) * 16 + ((lane >> 1) & 1) * 8;
  {
    int v0 = __builtin_amdgcn_cvt_pk_fp8_f32(a0.x * sa, a0.y * sa, 0, false);
    v0 = __builtin_amdgcn_cvt_pk_fp8_f32(a0.z * sa, a0.w * sa, v0, true);
    int v1 = __builtin_amdgcn_cvt_pk_fp8_f32(a1.x * sa, a1.y * sa, 0, false);
    v1 = __builtin_amdgcn_cvt_pk_fp8_f32(a1.z * sa, a1.w * sa, v1, true);
    int2 pv; pv.x = v0; pv.y = v1;
    *(int2*)(An + (size_t)row * DK + doff) = pv;
  }
  {
    int v0 = __builtin_amdgcn_cvt_pk_fp8_f32(b0.x * sb, b0.y * sb, 0, false);
    v0 = __builtin_amdgcn_cvt_pk_fp8_f32(b0.z * sb, b0.w * sb, v0, true);
    int v1 = __builtin_amdgcn_cvt_pk_fp8_f32(b1.x * sb, b1.y * sb, 0, false);
    v1 = __builtin_amdgcn_cvt_pk_fp8_f32(b1.z * sb, b1.w * sb, v1, true);
    int2 pv; pv.x = v0; pv.y = v1;
    *(int2*)(Bn + (size_t)row * DK + doff) = pv;
  }
  if (lane == 0) diag[row] = (sab / (na * nb)) * 10.0f;  // exact fp32 /TAU
}

// ---------------- tiles: MX fp8 MFMA, 128-row blocks, 2 passes, dbuf ------
// grid = (32 row-blocks, 16 col-splits) = 512 blocks = 2/CU. 4 waves/block,
// wave owns 32 rows. Pass 0 (u<8): a-frags -> full_a sum+max. Pass 1:
// b-frags -> full_b sums. Tiles restaged per pass (4MB dataset, L2-hot).
__global__ void __launch_bounds__(256, 2) tiles_kernel(
    const unsigned char* __restrict__ An, const unsigned char* __restrict__ Bn,
    float* __restrict__ pSA, float* __restrict__ pMA, float* __restrict__ pSB) {
  __shared__ __align__(16) unsigned char smem[2 * TILE_BYTES];  // 64 KB

  const int rb = blockIdx.x;     // 0..31 (128-row panel)
  const int split = blockIdx.y;  // 0..15 (8 j-tiles each)
  const int tid = threadIdx.x;
  const int lane = tid & 63, w = tid >> 6;
  const int n5 = lane & 31, h = lane >> 5;
  const int r0 = rb * 128;
  const int myrow = r0 + w * 32 + n5;

  // one view's left K=64 MX operands: aw[i] = chunks (2i,h)||(2i+1,h)
  intx8 aw[8];
  auto loadfrags = [&](const unsigned char* base) {
    const unsigned char* p = base + (size_t)myrow * DK + h * 16;
#pragma unroll
    for (int i = 0; i < 8; ++i) {
      int4 c0 = *(const int4*)(p + i * 64);        // chunk kc2=2i
      int4 c1 = *(const int4*)(p + i * 64 + 32);   // chunk kc2=2i+1
      intx8 v = {c0.x, c0.y, c0.z, c0.w, c1.x, c1.y, c1.z, c1.w};
      aw[i] = v;
    }
  };

  // fixed-max state: l[r] = sum exp(logit-10); mx[r] = max acc (pass A only)
  float l[16], mx[16];
#pragma unroll
  for (int r = 0; r < 16; ++r) { l[r] = 0.f; mx[r] = NEG_BIG; }

  // stage a 64-col fp8 tile; one inst = 2 cols (h=0 even, h=1 odd).
  // XOR swizzle: physical 16B chunk p of col c holds logical chunk p^(c&7).
  auto stage = [&](unsigned char* buf, int jt) {
    const unsigned char* csrc = (jt < 64) ? An : Bn;
    const int cb = (jt & 63) * 64;
#pragma unroll
    for (int ii = 0; ii < 8; ++ii) {  // wave w: colpairs w*8 .. w*8+7
      const int cp = w * 8 + ii;
      const int cl = cp * 2 + h;
      const unsigned char* src =
          csrc + (size_t)(cb + cl) * DK + ((n5 ^ (cl & 7)) * 16);
      __builtin_amdgcn_global_load_lds(
          (const __attribute__((address_space(1))) void*)src,
          (__attribute__((address_space(3))) void*)(buf + cp * 1024),
          16, 0, 0);
    }
  };

  stage(smem, split * 8);
  loadfrags(An);
  __syncthreads();

  const int swz = n5 & 7;
  for (int u = 0; u < 16; ++u) {
    const int t = u & 7;
    const int jt = split * 8 + t;
    unsigned char* cur = smem + (u & 1) * TILE_BYTES;
    unsigned char* nxt = smem + ((u + 1) & 1) * TILE_BYTES;
    if (u < 15) stage(nxt, split * 8 + ((t + 1) & 7));  // prefetch

    floatx16 acc[2];
#pragma unroll
    for (int cs = 0; cs < 2; ++cs)
#pragma unroll
      for (int r = 0; r < 16; ++r) acc[cs][r] = 0.f;

    // B K=64 operand: logical chunks (4i+h) and (4i+2+h) of col cs*32+n5
    const unsigned char* bbase = cur + (size_t)n5 * DK;
#pragma unroll
    for (int i = 0; i < 8; ++i) {
      const int p1 = ((4 * i + h) ^ swz) * 16;
      const int p2 = ((4 * i + 2 + h) ^ swz) * 16;
#pragma unroll
      for (int cs = 0; cs < 2; ++cs) {
        int4 b0 = *(const int4*)(bbase + cs * 32 * DK + p1);
        int4 b1 = *(const int4*)(bbase + cs * 32 * DK + p2);
        intx8 bw = {b0.x, b0.y, b0.z, b0.w, b1.x, b1.y, b1.z, b1.w};
        acc[cs] = __builtin_amdgcn_mfma_scale_f32_32x32x64_f8f6f4(
            aw[i], bw, acc[cs], 0, 0, 0, 0x7F7F7F7F, 0, 0x7F7F7F7F);
      }
    }

    // epilogue: mask (i,i) of this half (aa/bb masked diag AND ab label —
    // label re-added exactly in finalize), exp-sum at fixed max 10.
    const bool dtile = (((jt & 63) >> 1) == rb);
    const int colbase = (jt & 63) * 64;
    const bool passA = (u < 8);
#pragma unroll
    for (int r = 0; r < 16; ++r) {
      float v0 = acc[0][r], v1 = acc[1][r];
      if (dtile) {
        const int rowg = r0 + w * 32 + (r & 3) + 8 * (r >> 2) + 4 * h;
        if (rowg == colbase + n5)      v0 = NEG_BIG;
        if (rowg == colbase + 32 + n5) v1 = NEG_BIG;
      }
      if (passA) mx[r] = fmaxf(mx[r], fmaxf(v0, v1));
      l[r] += exp2f(fmaf(v0, SCL2, -C2)) + exp2f(fmaf(v1, SCL2, -C2));
    }

    if (u == 7) {  // pass boundary: emit full_a stats, switch to b-frags
#pragma unroll
      for (int off = 1; off < 32; off <<= 1)
#pragma unroll
        for (int r = 0; r < 16; ++r) {
          l[r] += __shfl_xor(l[r], off);
          mx[r] = fmaxf(mx[r], __shfl_xor(mx[r], off));
        }
      if (n5 == 0) {
#pragma unroll
        for (int r = 0; r < 16; ++r) {
          const int row = r0 + w * 32 + (r & 3) + 8 * (r >> 2) + 4 * h;
          pSA[split * BN + row] = l[r];
          pMA[split * BN + row] = mx[r] * SCL;  // logit-domain max
        }
      }
#pragma unroll
      for (int r = 0; r < 16; ++r) l[r] = 0.f;
      loadfrags(Bn);
    }
    __syncthreads();  // cur consumed; nxt's DMA drained
  }

  // emit full_b sums
#pragma unroll
  for (int off = 1; off < 32; off <<= 1)
#pragma unroll
    for (int r = 0; r < 16; ++r) l[r] += __shfl_xor(l[r], off);
  if (n5 == 0) {
#pragma unroll
    for (int r = 0; r < 16; ++r) {
      const int row = r0 + w * 32 + (r & 3) + 8 * (r >> 2) + 4 * h;
      pSB[split * BN + row] = l[r];
    }
  }
}

// ---------------- finalize: merge 16 splits, add label, reduce ------------
__global__ void __launch_bounds__(256) finalize_kernel(
    const float* __restrict__ pSA, const float* __restrict__ pMA,
    const float* __restrict__ pSB, const float* __restrict__ diag,
    float* __restrict__ out) {
  const int row = blockIdx.x * 256 + threadIdx.x;
  float SA = 0.f, SB = 0.f, MA = NEG_BIG;
#pragma unroll
  for (int s = 0; s < NSPLIT; ++s) {
    SA += pSA[s * BN + row];
    SB += pSB[s * BN + row];
    MA = fmaxf(MA, pMA[s * BN + row]);
  }
  const float d = diag[row];
  const float eL = exp2f(fmaf(d, 1.44269504f, -C2));  // exp(d-10)
  float lseA = 10.0f + logf(SA + eL);
  float lseB = 10.0f + logf(SB + eL);
  float lossi = (lseA - d) + (lseB - d);
  float corr = (d >= MA) ? 1.f : 0.f;  // argmax(full_a)==label
#pragma unroll
  for (int off = 32; off > 0; off >>= 1) {
    lossi += __shfl_xor(lossi, off);
    corr += __shfl_xor(corr, off);
  }
  __shared__ float sred[2][4];
  if ((threadIdx.x & 63) == 0) {
    int w = threadIdx.x >> 6;
    sred[0][w] = lossi; sred[1][w] = corr;
  }
  __syncthreads();
  if (threadIdx.x == 0) {
    float ls = sred[0][0] + sred[0][1] + sred[0][2] + sred[0][3];
    float cs = sred[1][0] + sred[1][1] + sred[1][2] + sred[1][3];
    atomicAdd(&out[0], ls * (1.0f / 8192.0f));    // mean over rows, /2
    atomicAdd(&out[1], cs * (100.0f / 4096.0f));  // accuracy %
  }
}

extern "C" void kernel_launch(void* const* d_in, const int* in_sizes, int n_in,
                              void* d_out, int out_size, void* d_ws, size_t ws_size,
                              hipStream_t stream) {
  const float* A = (const float*)d_in[0];
  const float* Bv = (const float*)d_in[1];
  unsigned char* An = (unsigned char*)d_ws;                   // 4096x512 fp8
  unsigned char* Bn = An + (size_t)BN * DK;                   // 4096x512 fp8
  float* diag = (float*)(Bn + (size_t)BN * DK);               // 4096 f32
  float* pSA = diag + BN;                                     // [16][4096] f32
  float* pMA = pSA + NSPLIT * BN;                             // [16][4096] f32
  float* pSB = pMA + NSPLIT * BN;                             // [16][4096] f32
  float* out = (float*)d_out;

  prep_kernel<<<BN / 4, 256, 0, stream>>>(A, Bv, An, Bn, diag, out);
  tiles_kernel<<<dim3(32, 16), 256, 0, stream>>>(An, Bn, pSA, pMA, pSB);
  finalize_kernel<<<BN / 256, 256, 0, stream>>>(pSA, pMA, pSB, diag, out);
}